// Round 9
// baseline (463.640 us; speedup 1.0000x reference)
//
#include <hip/hip_runtime.h>
#include <hip/hip_bf16.h>

// ---------------- shapes ----------------
#define Bdim 2
#define Tdim 1024
#define DMODEL 2048
#define DSTATE 64
#define HEADDIM 64
#define DCONV 4
#define DINNER 4096
#define NHEADS 64
#define CONVDIM 4224           // DINNER + 2*DSTATE
#define DINPROJ 8384           // 2*DINNER + 2*DSTATE + NHEADS
#define NPAD 8448              // DINPROJ padded to multiple of 128
#define MROWS (Bdim*Tdim)      // 2048
#define QC 64                  // scan chunk length
#define NCHUNK (Tdim/QC)       // 16

typedef __attribute__((ext_vector_type(8))) short bf16x8;
typedef __attribute__((ext_vector_type(4))) float f32x4;
typedef __attribute__((ext_vector_type(4))) unsigned short u16x4;
typedef __attribute__((ext_vector_type(8))) unsigned short u16x8;

#define GLB(p) ((const __attribute__((address_space(1))) void*)(p))
#define LDS(p) ((__attribute__((address_space(3))) void*)(p))

__device__ __forceinline__ unsigned short f2bf(float f) {
    unsigned int x = __builtin_bit_cast(unsigned int, f);
    x += 0x7fffu + ((x >> 16) & 1u);   // RNE
    return (unsigned short)(x >> 16);
}
__device__ __forceinline__ float bf2f(unsigned int u16) {
    unsigned int x = u16 << 16;
    return __builtin_bit_cast(float, x);
}
__device__ __forceinline__ float siluf(float v) {
    return v / (1.f + expf(-v));
}

// ------- fused prep: fp32->bf16 weight convert + LayerNorm -------------------
#define CVT_A4 (NPAD * DMODEL / 4)        // 4,325,376
#define CVT_B4 (DMODEL * DINNER / 4)      // 2,097,152
#define CVT_BLKS ((CVT_A4 + CVT_B4) / 256)  // 25088
__global__ __launch_bounds__(256) void prep_k(const float* __restrict__ in_proj,
                                              const float* __restrict__ out_proj,
                                              unsigned short* __restrict__ win,
                                              unsigned short* __restrict__ wout,
                                              const float* __restrict__ x,
                                              const float* __restrict__ lw,
                                              const float* __restrict__ lb,
                                              unsigned short* __restrict__ u) {
    if (blockIdx.x < CVT_BLKS) {
        int idx = blockIdx.x * 256 + threadIdx.x;
        if (idx < CVT_A4) {
            int i4 = idx * 4;
            int row = i4 >> 11;               // /DMODEL
            u16x4 o;
            if (row < DINPROJ) {
                float4 v = *(const float4*)(in_proj + i4);
                o = (u16x4){f2bf(v.x), f2bf(v.y), f2bf(v.z), f2bf(v.w)};
            } else {
                o = (u16x4){0, 0, 0, 0};
            }
            *(u16x4*)(win + i4) = o;
        } else {
            int i4 = (idx - CVT_A4) * 4;
            float4 v = *(const float4*)(out_proj + i4);
            *(u16x4*)(wout + i4) = (u16x4){f2bf(v.x), f2bf(v.y), f2bf(v.z), f2bf(v.w)};
        }
        return;
    }
    // ---- layernorm rows ----
    int row = blockIdx.x - CVT_BLKS;
    const float* xr = x + (size_t)row * DMODEL;
    float4 v[2];
    float s = 0.f, s2 = 0.f;
#pragma unroll
    for (int i = 0; i < 2; ++i) {
        int c = (threadIdx.x + 256 * i) * 4;
        v[i] = *(const float4*)(xr + c);
        s += v[i].x + v[i].y + v[i].z + v[i].w;
        s2 += v[i].x * v[i].x + v[i].y * v[i].y + v[i].z * v[i].z + v[i].w * v[i].w;
    }
#pragma unroll
    for (int off = 32; off; off >>= 1) { s += __shfl_down(s, off); s2 += __shfl_down(s2, off); }
    __shared__ float rs[4], rs2[4];
    if ((threadIdx.x & 63) == 0) { rs[threadIdx.x >> 6] = s; rs2[threadIdx.x >> 6] = s2; }
    __syncthreads();
    s = rs[0] + rs[1] + rs[2] + rs[3];
    s2 = rs2[0] + rs2[1] + rs2[2] + rs2[3];
    float mu = s * (1.f / DMODEL);
    float var = s2 * (1.f / DMODEL) - mu * mu;
    float inv = rsqrtf(var + 1e-5f);
#pragma unroll
    for (int i = 0; i < 2; ++i) {
        int c = (threadIdx.x + 256 * i) * 4;
        float4 wv = *(const float4*)(lw + c);
        float4 bv = *(const float4*)(lb + c);
        u16x4 o = {f2bf((v[i].x - mu) * inv * wv.x + bv.x),
                   f2bf((v[i].y - mu) * inv * wv.y + bv.y),
                   f2bf((v[i].z - mu) * inv * wv.z + bv.z),
                   f2bf((v[i].w - mu) * inv * wv.w + bv.w)};
        *(u16x4*)(u + (size_t)row * DMODEL + c) = o;
    }
}

#define WAITV(n) asm volatile("s_waitcnt vmcnt(" #n ")" ::: "memory")
#define LGKM0   do { asm volatile("s_waitcnt lgkmcnt(0)" ::: "memory"); \
                     __builtin_amdgcn_sched_barrier(0); } while (0)
#define SCB     __builtin_amdgcn_sched_barrier(0)
#define BAR     __builtin_amdgcn_s_barrier()

// ====== GEMM1: BM=256/BN=128/BK=32, 8 waves, per-wave 64x64, 2 blocks/CU =====
// LDS model (validated R8, 3%): per K-tile LDS = 64 ds_read_b128 x 12 +
// stage-write 192 = 960 cyc for 2.1 MFLOP -> 2185 FLOP/LDS-cyc (1.4x the R8
// config).  48 KiB LDS, VGPR ~95 -> 2 blocks/CU (16 waves).  Schedule = R8's
// proven counted-wait anatomy, single phase per K-tile (WAITV(3), vmcnt(0)
// only at tail).  LDS layout = R4/R5-proven pair-packed BK=32 swizzle
// (measured 0 bank conflicts): rows 2rp,2rp+1 share 128B line rp; slot s
// holds g'=s^(rp&7): row=2rp+(g'>>2), kchunk=g'&3.  Fragment read slot
// s=(((row&1)<<2)+quad)^(rp&7) -> 2 lanes/bank (free).
template <int KTILES>
__global__ __launch_bounds__(512, 4) void gemm1_k32(const unsigned short* __restrict__ A,
                                                    const unsigned short* __restrict__ Bw,
                                                    float* __restrict__ Cout,
                                                    int N, int lda, int ldb,
                                                    int nb, int mb) {
    constexpr int BM = 256, BN = 128;
    __shared__ unsigned short As[2][BM * 32];   // 16 KiB each
    __shared__ unsigned short Bs[2][BN * 32];   //  8 KiB each

    // panel swizzle (8 n-tiles per panel) for L2 reuse
    const int bid = blockIdx.x;
    const int per_panel = mb * 8;
    const int fullp = (nb / 8) * per_panel;
    int mt, nt;
    if (bid < fullp) {
        int p = bid / per_panel, r = bid % per_panel;
        nt = p * 8 + r / mb; mt = r % mb;
    } else {
        int r = bid - fullp;
        nt = (nb / 8) * 8 + r / mb; mt = r % mb;
    }
    const int m0 = mt * BM, n0 = nt * BN;

    const int tid = threadIdx.x;
    const int lane = tid & 63, w = tid >> 6;
    const int wm = (w >> 1) * 64;    // 4 M-waves
    const int wn = (w & 1) * 64;     // 2 N-waves
    const int row16 = lane & 15, quad = lane >> 4;

    // staging sources (A: 1024 chunks -> 2/thread, B: 512 -> 1/thread)
    const unsigned short* gA[2];
    const unsigned short* gB0;
#pragma unroll
    for (int l = 0; l < 2; ++l) {
        int c = l * 512 + tid, rp = c >> 3, gp = (c & 7) ^ (rp & 7);
        int row = rp * 2 + (gp >> 2), kb = gp & 3;
        gA[l] = A + (size_t)(m0 + row) * lda + kb * 8;
    }
    {
        int c = tid, rp = c >> 3, gp = (c & 7) ^ (rp & 7);
        int row = rp * 2 + (gp >> 2), kb = gp & 3;
        gB0 = Bw + (size_t)(n0 + row) * ldb + kb * 8;
    }

    // fragment LDS offsets (shorts)
    int aoff[4], boff[4];
#pragma unroll
    for (int i = 0; i < 4; ++i) {
        int row = wm + i * 16 + row16, rp = row >> 1;
        int s = (((row & 1) << 2) + quad) ^ (rp & 7);
        aoff[i] = rp * 64 + s * 8;
    }
#pragma unroll
    for (int j = 0; j < 4; ++j) {
        int row = wn + j * 16 + row16, rp = row >> 1;
        int s = (((row & 1) << 2) + quad) ^ (rp & 7);
        boff[j] = rp * 64 + s * 8;
    }

#define STG(d, kt) do {                                                            \
    __builtin_amdgcn_global_load_lds(GLB(gA[0] + (kt) * 32),                       \
                                     LDS(&As[d][tid * 8]), 16, 0, 0);              \
    __builtin_amdgcn_global_load_lds(GLB(gA[1] + (kt) * 32),                       \
                                     LDS(&As[d][(512 + tid) * 8]), 16, 0, 0);      \
    __builtin_amdgcn_global_load_lds(GLB(gB0 + (kt) * 32),                         \
                                     LDS(&Bs[d][tid * 8]), 16, 0, 0);              \
} while (0)

    f32x4 acc[4][4];
#pragma unroll
    for (int i = 0; i < 4; ++i)
#pragma unroll
        for (int j = 0; j < 4; ++j) acc[i][j] = (f32x4){0.f, 0.f, 0.f, 0.f};
    bf16x8 bfr[4], af[4];

    STG(0, 0);                           // 3 outstanding (tile 0)
    int cur = 0;
    for (int t = 0; t < KTILES; ++t) {
        if (t + 1 < KTILES) {
            STG(cur ^ 1, t + 1);         // +3 -> 6 outstanding
            WAITV(3);                    // retire tile t's 3; keep t+1 in flight
        } else {
            WAITV(0);                    // tail drain (once per block)
        }
        BAR;                             // tile t visible to all waves
#pragma unroll
        for (int j = 0; j < 4; ++j) bfr[j] = *(const bf16x8*)&Bs[cur][boff[j]];
#pragma unroll
        for (int i = 0; i < 4; ++i) af[i] = *(const bf16x8*)&As[cur][aoff[i]];
        LGKM0;
        __builtin_amdgcn_s_setprio(1);
#pragma unroll
        for (int i = 0; i < 4; ++i)
#pragma unroll
            for (int j = 0; j < 4; ++j)
                acc[i][j] = __builtin_amdgcn_mfma_f32_16x16x32_bf16(af[i], bfr[j], acc[i][j], 0, 0, 0);
        __builtin_amdgcn_s_setprio(0);
        BAR;                             // reads done -> buffer reusable
        cur ^= 1;
    }

#pragma unroll
    for (int i = 0; i < 4; ++i)
#pragma unroll
        for (int j = 0; j < 4; ++j)
#pragma unroll
            for (int r = 0; r < 4; ++r) {
                int m = m0 + wm + i * 16 + quad * 4 + r;
                int n = n0 + wn + j * 16 + row16;
                Cout[(size_t)m * N + n] = acc[i][j][r];
            }
#undef STG
}

// ====== co-resident gemm8-anatomy GEMM (R8-measured), NT-parameterized =======
// 4-phase schedule, 2 LDS buffers, counted WAITV(NA), XOR chunk swizzle
// (all proven).  NT=512: wave grid 4x2; NT=256: 2x2.
template <int EPI, int NT, int BM, int BN, int KTILES>
__global__ __launch_bounds__(NT, 4) void gemm_cr(const unsigned short* __restrict__ A,
                                                 const unsigned short* __restrict__ Bw,
                                                 float* __restrict__ Cout,
                                                 const float* __restrict__ resid,
                                                 int N, int lda, int ldb,
                                                 int nb, int mb) {
    constexpr int MW = NT / 128;          // M-waves (4 or 2)
    constexpr int NA = BM * 64 / 8 / NT;  // A chunks per thread per K-tile
    constexpr int NB = BN * 64 / 8 / NT;  // B chunks per thread per K-tile
    constexpr int IM = BM / MW / 16;      // A frags per wave
    constexpr int IMH = IM / 2;           // A frags per phase
    constexpr int IN = BN / 2 / 16;       // B frags per wave

    __shared__ unsigned short As[2][BM * 64];
    __shared__ unsigned short Bs[2][BN * 64];

    const int bid = blockIdx.x;
    const int per_panel = mb * 8;
    const int fullp = (nb / 8) * per_panel;
    int mt, nt;
    if (bid < fullp) {
        int p = bid / per_panel, r = bid % per_panel;
        nt = p * 8 + r / mb; mt = r % mb;
    } else {
        int r = bid - fullp;
        nt = (nb / 8) * 8 + r / mb; mt = r % mb;
    }
    const int m0 = mt * BM, n0 = nt * BN;

    const int tid = threadIdx.x;
    const int lane = tid & 63, w = tid >> 6;
    const int wm = (w >> 1) * (BM / MW);
    const int wn = (w & 1) * (BN / 2);
    const int row16 = lane & 15, quad = lane >> 4;
    const int swz = row16 & 7;

    const unsigned short* gA[NA];
    const unsigned short* gB[NB];
#pragma unroll
    for (int l = 0; l < NA; ++l) {
        int c = l * NT + tid, r = c >> 3, kb = (c & 7) ^ (r & 7);
        gA[l] = A + (size_t)(m0 + r) * lda + kb * 8;
    }
#pragma unroll
    for (int l = 0; l < NB; ++l) {
        int c = l * NT + tid, r = c >> 3, kb = (c & 7) ^ (r & 7);
        gB[l] = Bw + (size_t)(n0 + r) * ldb + kb * 8;
    }

#define STG_A(d, kt) do { _Pragma("unroll")                                           \
    for (int _l = 0; _l < NA; ++_l)                                                   \
        __builtin_amdgcn_global_load_lds(GLB(gA[_l] + (kt) * 64),                     \
                LDS(&As[d][(_l * NT + tid) * 8]), 16, 0, 0); } while (0)
#define STG_B(d, kt) do { _Pragma("unroll")                                           \
    for (int _l = 0; _l < NB; ++_l)                                                   \
        __builtin_amdgcn_global_load_lds(GLB(gB[_l] + (kt) * 64),                     \
                LDS(&Bs[d][(_l * NT + tid) * 8]), 16, 0, 0); } while (0)
#define WAITN() do { if constexpr (NA == 2) WAITV(2); else WAITV(4); } while (0)
#define RD_B(d) do { _Pragma("unroll") for (int _j = 0; _j < IN; ++_j)                \
                     _Pragma("unroll") for (int _kc = 0; _kc < 2; ++_kc) {            \
                         int _row = wn + _j * 16 + row16;                             \
                         int _g = (_kc * 4 + quad) ^ swz;                             \
                         bfr[_j][_kc] = *(const bf16x8*)&Bs[d][(_row * 8 + _g) * 8];  \
                     } } while (0)
#define RD_A(d, h) do { _Pragma("unroll") for (int _i = 0; _i < IMH; ++_i)            \
                        _Pragma("unroll") for (int _kc = 0; _kc < 2; ++_kc) {         \
                            int _row = wm + ((h) * IMH + _i) * 16 + row16;            \
                            int _g = (_kc * 4 + quad) ^ swz;                          \
                            af[_i][_kc] = *(const bf16x8*)&As[d][(_row * 8 + _g) * 8];\
                        } } while (0)
#define MM(h) do { __builtin_amdgcn_s_setprio(1);                                     \
                   _Pragma("unroll") for (int _kc = 0; _kc < 2; ++_kc)                \
                   _Pragma("unroll") for (int _i = 0; _i < IMH; ++_i)                 \
                   _Pragma("unroll") for (int _j = 0; _j < IN; ++_j)                  \
                       acc[(h) * IMH + _i][_j] = __builtin_amdgcn_mfma_f32_16x16x32_bf16( \
                           af[_i][_kc], bfr[_j][_kc], acc[(h) * IMH + _i][_j], 0, 0, 0);  \
                   __builtin_amdgcn_s_setprio(0); } while (0)

    f32x4 acc[IM][IN];
#pragma unroll
    for (int i = 0; i < IM; ++i)
#pragma unroll
        for (int j = 0; j < IN; ++j) acc[i][j] = (f32x4){0.f, 0.f, 0.f, 0.f};
    bf16x8 bfr[IN][2], af[IMH][2];

    // prologue: stage K-tile 0 into dbuf0
    STG_A(0, 0); STG_B(0, 0);

    const int KI = KTILES / 2;
    for (int i = 0; i < KI; ++i) {
        const int k1 = 2 * i + 1, k2 = 2 * i + 2;
        const bool st2 = (k2 < KTILES);
        // ---- phase 0: K-tile 2i (dbuf0), A-half 0 ----
        STG_A(1, k1);
        WAITN();
        BAR;
        RD_B(0); RD_A(0, 0);
        LGKM0;
        MM(0);
        BAR;
        // ---- phase 1: K-tile 2i (dbuf0), A-half 1 ----
        RD_A(0, 1);
        STG_B(1, k1);
        BAR;
        LGKM0;
        MM(1);
        BAR;
        // ---- phase 2: K-tile 2i+1 (dbuf1), A-half 0 ----
        if (st2) {
            STG_A(0, k2);
            WAITN();
        } else {
            WAITV(0);
        }
        BAR;
        RD_B(1); RD_A(1, 0);
        LGKM0;
        MM(0);
        BAR;
        // ---- phase 3: K-tile 2i+1 (dbuf1), A-half 1 ----
        RD_A(1, 1);
        if (st2) STG_B(0, k2);
        BAR;
        LGKM0;
        MM(1);
        BAR;
    }

#pragma unroll
    for (int i = 0; i < IM; ++i)
#pragma unroll
        for (int j = 0; j < IN; ++j)
#pragma unroll
            for (int r = 0; r < 4; ++r) {
                int m = m0 + wm + i * 16 + quad * 4 + r;
                int n = n0 + wn + j * 16 + row16;
                float v = acc[i][j][r];
                if (EPI == 0)
                    Cout[(size_t)m * N + n] = v;
                else
                    Cout[(size_t)m * N + n] = resid[(size_t)m * N + n] + v;
            }
#undef STG_A
#undef STG_B
#undef WAITN
#undef RD_A
#undef RD_B
#undef MM
}

// -------- fused causal conv4+SiLU (vec4) + dt/softplus (vec4) ----------------
#define CONV_T (MROWS * CONVDIM / 4)      // 2,162,688
__global__ __launch_bounds__(256) void convdt_k(const float* __restrict__ zx,
                                                const float* __restrict__ cw,
                                                const float* __restrict__ cb,
                                                const float* __restrict__ dt_bias,
                                                const float* __restrict__ A_log,
                                                float* __restrict__ xin,
                                                float* __restrict__ bcf,
                                                float* __restrict__ dtf,
                                                float* __restrict__ dtAf) {
    int idx = blockIdx.x * 256 + threadIdx.x;
    if (idx < CONV_T) {
        int cg = idx % (CONVDIM / 4);
        int bt = idx / (CONVDIM / 4);
        int c = cg * 4;
        int t = bt & (Tdim - 1);
        const float* base = zx + (size_t)bt * NPAD + DINNER + c;
        float4 acc = *(const float4*)(cb + c);
#pragma unroll
        for (int kk = 0; kk < DCONV; ++kk) {
            int tt = t - 3 + kk;
            if (tt >= 0) {
                float4 v = *(const float4*)(base + (long)(kk - 3) * NPAD);
                acc.x += v.x * cw[(c + 0) * 4 + kk];
                acc.y += v.y * cw[(c + 1) * 4 + kk];
                acc.z += v.z * cw[(c + 2) * 4 + kk];
                acc.w += v.w * cw[(c + 3) * 4 + kk];
            }
        }
        float4 s = {siluf(acc.x), siluf(acc.y), siluf(acc.z), siluf(acc.w)};
        if (c < DINNER) *(float4*)(xin + (size_t)bt * DINNER + c) = s;
        else            *(float4*)(bcf + (size_t)bt * 128 + (c - DINNER)) = s;
    } else {
        int d4 = (idx - CONV_T) * 4;
        int bt = d4 >> 6;
        int h = d4 & 63;
        float4 raw = *(const float4*)(zx + (size_t)bt * NPAD + (DINNER + CONVDIM) + h);
        float4 bias = *(const float4*)(dt_bias + h);
        float4 al = *(const float4*)(A_log + h);
        float r[4] = {raw.x + bias.x, raw.y + bias.y, raw.z + bias.z, raw.w + bias.w};
        float A[4] = {-expf(al.x), -expf(al.y), -expf(al.z), -expf(al.w)};
        float4 dtv, dta;
        float* dtp = (float*)&dtv; float* dap = (float*)&dta;
#pragma unroll
        for (int j = 0; j < 4; ++j) {
            float dv = (r[j] > 20.f) ? r[j] : log1pf(expf(r[j]));
            dtp[j] = dv;
            dap[j] = dv * A[j];
        }
        *(float4*)(dtf + bt * 64 + h) = dtv;
        *(float4*)(dtAf + bt * 64 + h) = dta;
    }
}

// ============ chunked SSM scan (SSD decomposition), Q=64 =====================
__global__ __launch_bounds__(256) void chunk_state_k(const float* __restrict__ xin,
                                                     const float* __restrict__ bcf,
                                                     const float* __restrict__ dtf,
                                                     const float* __restrict__ dtAf,
                                                     float* __restrict__ Sst,
                                                     float* __restrict__ laq) {
    const int blk = blockIdx.x;
    const int c = blk & 15, h = (blk >> 4) & 63, b = blk >> 10;
    const int bt0 = b * Tdim + c * QC;
    const int tid = threadIdx.x;

    __shared__ float Bs[QC][68];
    __shared__ float Dx[QC][68];
    __shared__ float wsh[QC];

    if (tid < QC) {
        float v = dtAf[(bt0 + tid) * NHEADS + h];
#pragma unroll
        for (int d = 1; d < 64; d <<= 1) {
            float o = __shfl_up(v, d, 64);
            v += (tid >= d) ? o : 0.f;
        }
        float la63 = __shfl(v, 63, 64);
        wsh[tid] = expf(la63 - v);
        if (tid == 63) laq[blk] = la63;
    }
    __syncthreads();

    const int row = tid >> 2, q = tid & 3;
    {
        float m = wsh[row] * dtf[(bt0 + row) * NHEADS + h];
        const float* xr = xin + (size_t)(bt0 + row) * DINNER + h * 64 + q * 16;
        const float* br = bcf + (size_t)(bt0 + row) * 128 + q * 16;
#pragma unroll
        for (int j = 0; j < 4; ++j) {
            float4 xv = *(const float4*)(xr + j * 4);
            float4 bv = *(const float4*)(br + j * 4);
            *(float4*)&Dx[row][q * 16 + j * 4] = (float4){m * xv.x, m * xv.y, m * xv.z, m * xv.w};
            *(float4*)&Bs[row][q * 16 + j * 4] = bv;
        }
    }
    __syncthreads();

    const int p0 = (tid >> 4) * 4, n0 = (tid & 15) * 4;
    float acc[4][4] = {};
    for (int i = 0; i < QC; ++i) {
        float4 dv = *(const float4*)&Dx[i][p0];
        float4 bv = *(const float4*)&Bs[i][n0];
        float dva[4] = {dv.x, dv.y, dv.z, dv.w};
        float bva[4] = {bv.x, bv.y, bv.z, bv.w};
#pragma unroll
        for (int a = 0; a < 4; ++a)
#pragma unroll
            for (int e = 0; e < 4; ++e) acc[a][e] += dva[a] * bva[e];
    }
    float* Sp = Sst + (size_t)blk * NPAD;
#pragma unroll
    for (int a = 0; a < 4; ++a)
        *(float4*)&Sp[(p0 + a) * 64 + n0] = (float4){acc[a][0], acc[a][1], acc[a][2], acc[a][3]};
}

// Phase B: 256 blocks, each handles half (32 rows) of one (b,h) state prefix
__global__ __launch_bounds__(256) void combine_k(float* __restrict__ Sst,
                                                 const float* __restrict__ laq) {
    const int bh = blockIdx.x >> 1;
    const int half = blockIdx.x & 1;
    const int tid = threadIdx.x;
    float4 r0 = {}, r1 = {};
    for (int c = 0; c < NCHUNK - 1; ++c) {
        float* p = Sst + (size_t)(bh * 16 + c) * NPAD + half * 2048 + tid * 8;
        float P = expf(laq[bh * 16 + c]);
        float4 s0 = ((const float4*)p)[0], s1 = ((const float4*)p)[1];
        r0 = (float4){P * r0.x + s0.x, P * r0.y + s0.y, P * r0.z + s0.z, P * r0.w + s0.w};
        r1 = (float4){P * r1.x + s1.x, P * r1.y + s1.y, P * r1.z + s1.z, P * r1.w + s1.w};
        ((float4*)p)[0] = r0; ((float4*)p)[1] = r1;
    }
}

// ======= chunk_out via MFMA: three 64x64x64 matmuls on the matrix pipe =======
__global__ __launch_bounds__(256) void chunk_out_k2(float* __restrict__ xin,
                                                    const float* __restrict__ bcf,
                                                    const float* __restrict__ dtf,
                                                    const float* __restrict__ dtAf,
                                                    const float* __restrict__ Sst,
                                                    const float* __restrict__ Dp) {
    const int blk = blockIdx.x;
    const int c = blk & 15, h = (blk >> 4) & 63, b = blk >> 10;
    const int bt0 = b * Tdim + c * QC;
    const int tid = threadIdx.x;

    __shared__ unsigned short Csh[64 * 64];   // [t][n]
    __shared__ unsigned short Bsh[64 * 64];   // [s][n]
    __shared__ unsigned short DxT[64 * 64];   // [p][s]
    __shared__ unsigned short Gh [64 * 64];   // [t][s]
    __shared__ unsigned short Hh [64 * 64];   // [p][n]
    __shared__ float lash[QC];

    if (tid < QC) {
        float v = dtAf[(bt0 + tid) * NHEADS + h];
#pragma unroll
        for (int d = 1; d < 64; d <<= 1) {
            float o = __shfl_up(v, d, 64);
            v += (tid >= d) ? o : 0.f;
        }
        lash[tid] = v;
    }

    const int row = tid >> 2, q = tid & 3;    // row = time (t/s) or p for Hh
    {
        float m = dtf[(bt0 + row) * NHEADS + h];
        const float* xr = xin + (size_t)(bt0 + row) * DINNER + h * 64 + q * 16;
        const float* br = bcf + (size_t)(bt0 + row) * 128 + q * 16;
        const float* cr = bcf + (size_t)(bt0 + row) * 128 + 64 + q * 16;
        float xb[16];
        u16x8 cc[2], bb[2];
#pragma unroll
        for (int j = 0; j < 4; ++j) {
            float4 xv = *(const float4*)(xr + j * 4);
            float4 bv = *(const float4*)(br + j * 4);
            float4 cv = *(const float4*)(cr + j * 4);
            xb[j * 4 + 0] = m * xv.x; xb[j * 4 + 1] = m * xv.y;
            xb[j * 4 + 2] = m * xv.z; xb[j * 4 + 3] = m * xv.w;
            int hi = j >> 1, lo = (j & 1) * 4;
            cc[hi][lo + 0] = f2bf(cv.x); cc[hi][lo + 1] = f2bf(cv.y);
            cc[hi][lo + 2] = f2bf(cv.z); cc[hi][lo + 3] = f2bf(cv.w);
            bb[hi][lo + 0] = f2bf(bv.x); bb[hi][lo + 1] = f2bf(bv.y);
            bb[hi][lo + 2] = f2bf(bv.z); bb[hi][lo + 3] = f2bf(bv.w);
        }
        const int base = row * 64;
        const int c0 = ((q * 2) ^ (row & 7)) * 8, c1 = ((q * 2 + 1) ^ (row & 7)) * 8;
        *(u16x8*)&Csh[base + c0] = cc[0];  *(u16x8*)&Csh[base + c1] = cc[1];
        *(u16x8*)&Bsh[base + c0] = bb[0];  *(u16x8*)&Bsh[base + c1] = bb[1];
        // DxT[p][s=row]: transpose scalar writes
#pragma unroll
        for (int k2 = 0; k2 < 16; ++k2) {
            int p = q * 16 + k2;
            DxT[p * 64 + (((row >> 3) ^ (p & 7)) * 8 + (row & 7))] = f2bf(xb[k2]);
        }
        if (c > 0) {   // Hh[p=row][n]: Sst layout is [p][n] -> row-major writes
            const float* Hp = Sst + (size_t)(blk - 1) * NPAD + row * 64 + q * 16;
            u16x8 hh[2];
#pragma unroll
            for (int j = 0; j < 4; ++j) {
                float4 hv = *(const float4*)(Hp + j * 4);
                int hi = j >> 1, lo = (j & 1) * 4;
                hh[hi][lo + 0] = f2bf(hv.x); hh[hi][lo + 1] = f2bf(hv.y);
                hh[hi][lo + 2] = f2bf(hv.z); hh[hi][lo + 3] = f2bf(hv.w);
            }
            *(u16x8*)&Hh[base + c0] = hh[0];  *(u16x8*)&Hh[base + c1] = hh[1];
        }
    }
    __syncthreads();

    const int lane = tid & 63, w = tid >> 6;
    const int t0 = w * 16;                    // wave's t-strip
    const int row16 = lane & 15, quad = lane >> 4;
    const int swz = row16 & 7;

    // ---- M1: acc1[t][s] ----
    f32x4 a1[4];
#pragma unroll
    for (int st = 0; st < 4; ++st) a1[st] = (f32x4){0.f, 0.f, 0.f, 0.f};
#pragma unroll
    for (int kc = 0; kc < 2; ++kc) {
        int g = ((kc * 4 + quad) ^ swz) * 8;
        bf16x8 ca = *(const bf16x8*)&Csh[(t0 + row16) * 64 + g];
#pragma unroll
        for (int st = 0; st < 4; ++st) {
            bf16x8 bs = *(const bf16x8*)&Bsh[(st * 16 + row16) * 64 + g];
            a1[st] = __builtin_amdgcn_mfma_f32_16x16x32_bf16(ca, bs, a1[st], 0, 0, 0);
        }
    }
    // ---- G[t][s] = mask * acc1 * exp(la_t - la_s), write bf16 to Gh ----
    float latv[4];
#pragma unroll
    for (int r = 0; r < 4; ++r) latv[r] = lash[t0 + quad * 4 + r];
#pragma unroll
    for (int st = 0; st < 4; ++st) {
        int s = st * 16 + row16;
        float las = lash[s];
#pragma unroll
        for (int r = 0; r < 4; ++r) {
            int t = t0 + quad * 4 + r;
            float gv = (s <= t) ? a1[st][r] * expf(latv[r] - las) : 0.f;
            Gh[t * 64 + (((s >> 3) ^ (t & 7)) * 8 + (s & 7))] = f2bf(gv);
        }
    }
    __syncthreads();

    // ---- M2 (+M3 when c>0) ----
    f32x4 aS[4], aH[4];
#pragma unroll
    for (int pt = 0; pt < 4; ++pt) { aS[pt] = (f32x4){0.f,0.f,0.f,0.f}; aH[pt] = (f32x4){0.f,0.f,0.f,0.f}; }
#pragma unroll
    for (int kc = 0; kc < 2; ++kc) {
        int g = ((kc * 4 + quad) ^ swz) * 8;
        bf16x8 ga = *(const bf16x8*)&Gh[(t0 + row16) * 64 + g];
#pragma unroll
        for (int pt = 0; pt < 4; ++pt) {
            bf16x8 db = *(const bf16x8*)&DxT[(pt * 16 + row16) * 64 + g];
            aS[pt] = __builtin_amdgcn_mfma_f32_16x16x32_bf16(ga, db, aS[pt], 0, 0, 0);
        }
        if (c > 0) {
            bf16x8 ca = *(const bf16x8*)&Csh[(t0 + row16) * 64 + g];
#pragma unroll
            for (int pt = 0; pt < 4; ++pt) {
                bf16x8 hb = *(const bf16x8*)&Hh[(pt * 16 + row16) * 64 + g];
                aH[pt] = __builtin_amdgcn_mfma_f32_16x16x32_bf16(ca, hb, aH[pt], 0, 0, 0);
            }
        }
    }

    // ---- epilogue: y = accS + e^{la_t} * accH + D*x ----
    float Dh = Dp[h];
    float eA[4];
#pragma unroll
    for (int r = 0; r < 4; ++r) eA[r] = expf(latv[r]);
#pragma unroll
    for (int pt = 0; pt < 4; ++pt)
#pragma unroll
        for (int r = 0; r < 4; ++r) {
            int t = t0 + quad * 4 + r, p = pt * 16 + row16;
            float* xr2 = xin + (size_t)(bt0 + t) * DINNER + h * 64 + p;
            float xv = *xr2;
            float y = aS[pt][r] + Dh * xv;
            if (c > 0) y += eA[r] * aH[pt][r];
            *xr2 = y;
        }
}

// ---------------- y * silu(z), RMSNorm, -> bf16 (strided dest, vec4) ---------
__global__ __launch_bounds__(256) void gate_k(const float* __restrict__ ybf,
                                              const float* __restrict__ zx,
                                              const float* __restrict__ nw,
                                              unsigned short* __restrict__ yg,
                                              int ldyg) {
    int row = blockIdx.x;
    float4 tv[4];
    float s2 = 0.f;
#pragma unroll
    for (int i = 0; i < 4; ++i) {
        int c = (threadIdx.x + 256 * i) * 4;
        float4 y = *(const float4*)(ybf + (size_t)row * DINNER + c);
        float4 z = *(const float4*)(zx + (size_t)row * NPAD + c);
        float4 t = {y.x * siluf(z.x), y.y * siluf(z.y), y.z * siluf(z.z), y.w * siluf(z.w)};
        tv[i] = t;
        s2 += t.x * t.x + t.y * t.y + t.z * t.z + t.w * t.w;
    }
#pragma unroll
    for (int off = 32; off; off >>= 1) s2 += __shfl_down(s2, off);
    __shared__ float rs[4];
    if ((threadIdx.x & 63) == 0) rs[threadIdx.x >> 6] = s2;
    __syncthreads();
    s2 = rs[0] + rs[1] + rs[2] + rs[3];
    float scale = rsqrtf(s2 * (1.f / DINNER) + 1e-5f);
#pragma unroll
    for (int i = 0; i < 4; ++i) {
        int c = (threadIdx.x + 256 * i) * 4;
        float4 w = *(const float4*)(nw + c);
        u16x4 o = {f2bf(tv[i].x * scale * w.x), f2bf(tv[i].y * scale * w.y),
                   f2bf(tv[i].z * scale * w.z), f2bf(tv[i].w * scale * w.w)};
        *(u16x4*)(yg + (size_t)row * ldyg + c) = o;
    }
}

// ---------------- launch ----------------
extern "C" void kernel_launch(void* const* d_in, const int* in_sizes, int n_in,
                              void* d_out, int out_size, void* d_ws, size_t ws_size,
                              hipStream_t stream) {
    const float* x        = (const float*)d_in[0];
    const float* ln_w     = (const float*)d_in[1];
    const float* ln_b     = (const float*)d_in[2];
    const float* in_proj  = (const float*)d_in[3];
    const float* conv_w   = (const float*)d_in[4];
    const float* conv_b   = (const float*)d_in[5];
    const float* dt_bias  = (const float*)d_in[6];
    const float* A_log    = (const float*)d_in[7];
    const float* Dp       = (const float*)d_in[8];
    const float* norm_w   = (const float*)d_in[9];
    const float* out_proj = (const float*)d_in[10];
    float* out = (float*)d_out;
    char* ws = (char*)d_ws;

    // ---- workspace layout ----
    float*          zx   = (float*)(ws + 0);                   // 2048 x 8448 fp32
    unsigned short* wout = (unsigned short*)(ws + 69206016);
    unsigned short* win  = (unsigned short*)(ws + 85983232);
    unsigned short* ubf  = (unsigned short*)(ws + 120586240);
    float*          xin  = (float*)(ws + 85983232);            // reuses win after GEMM1
    float*          bcf  = (float*)(ws + 120586240);           // reuses ubf
    float*          dtf  = (float*)(ws + 121634816);
    float*          dtAf = (float*)(ws + 122159104);
    float*          laq  = (float*)(ws + 122683392);           // 2048 floats
    float*          Sst  = zx + 4096;                          // dead xBC cols of zx
    unsigned short* yg   = (unsigned short*)zx + 8192;         // dead cols (bf16)
    const int       ldyg = 16896;

    prep_k<<<CVT_BLKS + MROWS, 256, 0, stream>>>(in_proj, out_proj, win, wout,
                                                 x, ln_w, ln_b, ubf);
    // GEMM1: M=2048 (BM=256 -> mb=8), N=8448 (BN=128 -> nb=66), K=2048 (64 tiles of 32)
    //        48 KiB LDS, ~95 VGPR -> 2 blocks/CU co-resident; grid 528
    gemm1_k32<64><<<66 * 8, 512, 0, stream>>>(ubf, win, zx, NPAD, DMODEL, DMODEL, 66, 8);
    convdt_k<<<(CONV_T + MROWS * NHEADS / 4) / 256, 256, 0, stream>>>(zx, conv_w, conv_b,
                                                                      dt_bias, A_log,
                                                                      xin, bcf, dtf, dtAf);
    chunk_state_k<<<Bdim * NHEADS * NCHUNK, 256, 0, stream>>>(xin, bcf, dtf, dtAf, Sst, laq);
    combine_k<<<2 * Bdim * NHEADS, 256, 0, stream>>>(Sst, laq);
    chunk_out_k2<<<Bdim * NHEADS * NCHUNK, 256, 0, stream>>>(xin, bcf, dtf, dtAf, Sst, Dp);
    gate_k<<<MROWS, 256, 0, stream>>>(xin, zx, norm_w, yg, ldyg);
    // GEMM2: M=2048 (BM=128 -> mb=16), N=2048 (BN=64 -> nb=32), K=4096 (64 tiles)
    //        4-wave blocks (NT=256), 48 KiB LDS; grid 512 -> 2 blocks/CU
    gemm_cr<1, 256, 128, 64, 64><<<32 * 16, 256, 0, stream>>>(yg, wout, out, x,
                                                              DMODEL, ldyg, DINNER, 32, 16);
}

// Round 10
// 393.903 us; speedup vs baseline: 1.1770x; 1.1770x over previous
//
#include <hip/hip_runtime.h>
#include <hip/hip_bf16.h>

// ---------------- shapes ----------------
#define Bdim 2
#define Tdim 1024
#define DMODEL 2048
#define DSTATE 64
#define HEADDIM 64
#define DCONV 4
#define DINNER 4096
#define NHEADS 64
#define CONVDIM 4224           // DINNER + 2*DSTATE
#define DINPROJ 8384           // 2*DINNER + 2*DSTATE + NHEADS
#define NPAD 8448              // DINPROJ padded to multiple of 128
#define MROWS (Bdim*Tdim)      // 2048
#define QC 64                  // scan chunk length
#define NCHUNK (Tdim/QC)       // 16

typedef __attribute__((ext_vector_type(8))) short bf16x8;
typedef __attribute__((ext_vector_type(4))) float f32x4;
typedef __attribute__((ext_vector_type(4))) unsigned short u16x4;
typedef __attribute__((ext_vector_type(8))) unsigned short u16x8;

#define GLB(p) ((const __attribute__((address_space(1))) void*)(p))
#define LDS(p) ((__attribute__((address_space(3))) void*)(p))

__device__ __forceinline__ unsigned short f2bf(float f) {
    unsigned int x = __builtin_bit_cast(unsigned int, f);
    x += 0x7fffu + ((x >> 16) & 1u);   // RNE
    return (unsigned short)(x >> 16);
}
__device__ __forceinline__ float bf2f(unsigned int u16) {
    unsigned int x = u16 << 16;
    return __builtin_bit_cast(float, x);
}
__device__ __forceinline__ float siluf(float v) {
    return v / (1.f + expf(-v));
}

// ------- fused prep: fp32->bf16 weight convert + LayerNorm -------------------
#define CVT_A4 (NPAD * DMODEL / 4)        // 4,325,376
#define CVT_B4 (DMODEL * DINNER / 4)      // 2,097,152
#define CVT_BLKS ((CVT_A4 + CVT_B4) / 256)  // 25088
__global__ __launch_bounds__(256) void prep_k(const float* __restrict__ in_proj,
                                              const float* __restrict__ out_proj,
                                              unsigned short* __restrict__ win,
                                              unsigned short* __restrict__ wout,
                                              const float* __restrict__ x,
                                              const float* __restrict__ lw,
                                              const float* __restrict__ lb,
                                              unsigned short* __restrict__ u) {
    if (blockIdx.x < CVT_BLKS) {
        int idx = blockIdx.x * 256 + threadIdx.x;
        if (idx < CVT_A4) {
            int i4 = idx * 4;
            int row = i4 >> 11;               // /DMODEL
            u16x4 o;
            if (row < DINPROJ) {
                float4 v = *(const float4*)(in_proj + i4);
                o = (u16x4){f2bf(v.x), f2bf(v.y), f2bf(v.z), f2bf(v.w)};
            } else {
                o = (u16x4){0, 0, 0, 0};
            }
            *(u16x4*)(win + i4) = o;
        } else {
            int i4 = (idx - CVT_A4) * 4;
            float4 v = *(const float4*)(out_proj + i4);
            *(u16x4*)(wout + i4) = (u16x4){f2bf(v.x), f2bf(v.y), f2bf(v.z), f2bf(v.w)};
        }
        return;
    }
    // ---- layernorm rows ----
    int row = blockIdx.x - CVT_BLKS;
    const float* xr = x + (size_t)row * DMODEL;
    float4 v[2];
    float s = 0.f, s2 = 0.f;
#pragma unroll
    for (int i = 0; i < 2; ++i) {
        int c = (threadIdx.x + 256 * i) * 4;
        v[i] = *(const float4*)(xr + c);
        s += v[i].x + v[i].y + v[i].z + v[i].w;
        s2 += v[i].x * v[i].x + v[i].y * v[i].y + v[i].z * v[i].z + v[i].w * v[i].w;
    }
#pragma unroll
    for (int off = 32; off; off >>= 1) { s += __shfl_down(s, off); s2 += __shfl_down(s2, off); }
    __shared__ float rs[4], rs2[4];
    if ((threadIdx.x & 63) == 0) { rs[threadIdx.x >> 6] = s; rs2[threadIdx.x >> 6] = s2; }
    __syncthreads();
    s = rs[0] + rs[1] + rs[2] + rs[3];
    s2 = rs2[0] + rs2[1] + rs2[2] + rs2[3];
    float mu = s * (1.f / DMODEL);
    float var = s2 * (1.f / DMODEL) - mu * mu;
    float inv = rsqrtf(var + 1e-5f);
#pragma unroll
    for (int i = 0; i < 2; ++i) {
        int c = (threadIdx.x + 256 * i) * 4;
        float4 wv = *(const float4*)(lw + c);
        float4 bv = *(const float4*)(lb + c);
        u16x4 o = {f2bf((v[i].x - mu) * inv * wv.x + bv.x),
                   f2bf((v[i].y - mu) * inv * wv.y + bv.y),
                   f2bf((v[i].z - mu) * inv * wv.z + bv.z),
                   f2bf((v[i].w - mu) * inv * wv.w + bv.w)};
        *(u16x4*)(u + (size_t)row * DMODEL + c) = o;
    }
}

#define WAITV(n) asm volatile("s_waitcnt vmcnt(" #n ")" ::: "memory")
#define LGKM0   do { asm volatile("s_waitcnt lgkmcnt(0)" ::: "memory"); \
                     __builtin_amdgcn_sched_barrier(0); } while (0)
#define SCB     __builtin_amdgcn_sched_barrier(0)
#define BAR     __builtin_amdgcn_s_barrier()

// ====== co-resident gemm8-anatomy GEMM (R8-measured best: GEMM1 93.5 us) =====
// 8 waves, wave grid 4M x 2N: per-wave (BM/4) x (BN/2).  4-phase schedule,
// 2 LDS buffers, counted WAITV(NA) once per K-tile, vmcnt(0) only at tail.
// XOR chunk swizzle (0 conflicts measured).  64 KiB LDS @BM=BN=128 ->
// 2 blocks/CU co-resident (cross-block overlap = the validated R8 lever).
template <int EPI, int BM, int BN, int KTILES>
__global__ __launch_bounds__(512, 4) void gemm_cr(const unsigned short* __restrict__ A,
                                                  const unsigned short* __restrict__ Bw,
                                                  float* __restrict__ Cout,
                                                  const float* __restrict__ resid,
                                                  int N, int lda, int ldb,
                                                  int nb, int mb) {
    constexpr int NA = BM / 64;     // A 16B-chunks per thread per K-tile
    constexpr int NB = BN / 64;     // B 16B-chunks per thread per K-tile
    constexpr int IM = BM / 64;     // A frags per wave ((BM/4)/16)
    constexpr int IMH = IM / 2;     // A frags per phase
    constexpr int IN = BN / 32;     // B frags per wave ((BN/2)/16)

    __shared__ unsigned short As[2][BM * 64];
    __shared__ unsigned short Bs[2][BN * 64];

    // panel swizzle (8 n-tiles per panel) for L2 reuse
    const int bid = blockIdx.x;
    const int per_panel = mb * 8;
    const int fullp = (nb / 8) * per_panel;
    int mt, nt;
    if (bid < fullp) {
        int p = bid / per_panel, r = bid % per_panel;
        nt = p * 8 + r / mb; mt = r % mb;
    } else {
        int r = bid - fullp;
        nt = (nb / 8) * 8 + r / mb; mt = r % mb;
    }
    const int m0 = mt * BM, n0 = nt * BN;

    const int tid = threadIdx.x;
    const int lane = tid & 63, w = tid >> 6;
    const int wm = (w >> 1) * (BM / 4);
    const int wn = (w & 1) * (BN / 2);
    const int row16 = lane & 15, quad = lane >> 4;
    const int swz = row16 & 7;

    const unsigned short* gA[NA];
    const unsigned short* gB[NB];
#pragma unroll
    for (int l = 0; l < NA; ++l) {
        int c = l * 512 + tid, r = c >> 3, kb = (c & 7) ^ (r & 7);
        gA[l] = A + (size_t)(m0 + r) * lda + kb * 8;
    }
#pragma unroll
    for (int l = 0; l < NB; ++l) {
        int c = l * 512 + tid, r = c >> 3, kb = (c & 7) ^ (r & 7);
        gB[l] = Bw + (size_t)(n0 + r) * ldb + kb * 8;
    }

#define STG_A(d, kt) do { _Pragma("unroll")                                           \
    for (int _l = 0; _l < NA; ++_l)                                                   \
        __builtin_amdgcn_global_load_lds(GLB(gA[_l] + (kt) * 64),                     \
                LDS(&As[d][(_l * 512 + tid) * 8]), 16, 0, 0); } while (0)
#define STG_B(d, kt) do { _Pragma("unroll")                                           \
    for (int _l = 0; _l < NB; ++_l)                                                   \
        __builtin_amdgcn_global_load_lds(GLB(gB[_l] + (kt) * 64),                     \
                LDS(&Bs[d][(_l * 512 + tid) * 8]), 16, 0, 0); } while (0)
#define WAITN() do { if constexpr (NA == 2) WAITV(2); else WAITV(4); } while (0)
#define RD_B(d) do { _Pragma("unroll") for (int _j = 0; _j < IN; ++_j)                \
                     _Pragma("unroll") for (int _kc = 0; _kc < 2; ++_kc) {            \
                         int _row = wn + _j * 16 + row16;                             \
                         int _g = (_kc * 4 + quad) ^ swz;                             \
                         bfr[_j][_kc] = *(const bf16x8*)&Bs[d][(_row * 8 + _g) * 8];  \
                     } } while (0)
#define RD_A(d, h) do { _Pragma("unroll") for (int _i = 0; _i < IMH; ++_i)            \
                        _Pragma("unroll") for (int _kc = 0; _kc < 2; ++_kc) {         \
                            int _row = wm + ((h) * IMH + _i) * 16 + row16;            \
                            int _g = (_kc * 4 + quad) ^ swz;                          \
                            af[_i][_kc] = *(const bf16x8*)&As[d][(_row * 8 + _g) * 8];\
                        } } while (0)
#define MM(h) do { __builtin_amdgcn_s_setprio(1);                                     \
                   _Pragma("unroll") for (int _kc = 0; _kc < 2; ++_kc)                \
                   _Pragma("unroll") for (int _i = 0; _i < IMH; ++_i)                 \
                   _Pragma("unroll") for (int _j = 0; _j < IN; ++_j)                  \
                       acc[(h) * IMH + _i][_j] = __builtin_amdgcn_mfma_f32_16x16x32_bf16( \
                           af[_i][_kc], bfr[_j][_kc], acc[(h) * IMH + _i][_j], 0, 0, 0);  \
                   __builtin_amdgcn_s_setprio(0); } while (0)

    f32x4 acc[IM][IN];
#pragma unroll
    for (int i = 0; i < IM; ++i)
#pragma unroll
        for (int j = 0; j < IN; ++j) acc[i][j] = (f32x4){0.f, 0.f, 0.f, 0.f};
    bf16x8 bfr[IN][2], af[IMH][2];

    // prologue: stage K-tile 0 into dbuf0
    STG_A(0, 0); STG_B(0, 0);

    const int KI = KTILES / 2;
    for (int i = 0; i < KI; ++i) {
        const int k1 = 2 * i + 1, k2 = 2 * i + 2;
        const bool st2 = (k2 < KTILES);
        // ---- phase 0: K-tile 2i (dbuf0), A-half 0 ----
        STG_A(1, k1);
        WAITN();                       // tile 2i landed (only k1's A outstanding)
        BAR;
        RD_B(0); RD_A(0, 0);
        LGKM0;
        MM(0);
        BAR;
        // ---- phase 1: K-tile 2i (dbuf0), A-half 1 ----
        RD_A(0, 1);
        STG_B(1, k1);
        BAR;
        LGKM0;
        MM(1);
        BAR;
        // ---- phase 2: K-tile 2i+1 (dbuf1), A-half 0 ----
        if (st2) {
            STG_A(0, k2);
            WAITN();                   // tile 2i+1 landed
        } else {
            WAITV(0);                  // tail drain (once per block)
        }
        BAR;
        RD_B(1); RD_A(1, 0);
        LGKM0;
        MM(0);
        BAR;
        // ---- phase 3: K-tile 2i+1 (dbuf1), A-half 1 ----
        RD_A(1, 1);
        if (st2) STG_B(0, k2);
        BAR;
        LGKM0;
        MM(1);
        BAR;
    }

#pragma unroll
    for (int i = 0; i < IM; ++i)
#pragma unroll
        for (int j = 0; j < IN; ++j)
#pragma unroll
            for (int r = 0; r < 4; ++r) {
                int m = m0 + wm + i * 16 + quad * 4 + r;
                int n = n0 + wn + j * 16 + row16;
                float v = acc[i][j][r];
                if (EPI == 0)
                    Cout[(size_t)m * N + n] = v;
                else
                    Cout[(size_t)m * N + n] = resid[(size_t)m * N + n] + v;
            }
#undef STG_A
#undef STG_B
#undef WAITN
#undef RD_A
#undef RD_B
#undef MM
}

// -------- conv4+SiLU with register-rolling taps (each zx element read ONCE) --
// Thread owns one 4-channel group for a TSEG-step t-segment; the 3 previous
// rows ride in registers (w0..w2).  Removes the ~4x HBM over-fetch of the
// per-(t,c) formulation.  dt/softplus path unchanged, in tail blocks.
#define CGRP (CONVDIM / 4)            // 1056
#define TSEG 32
#define SEGS (Tdim / TSEG)            // 32
#define CPART 5                       // ceil(1056/256)
#define CONV_BLKS (Bdim * SEGS * CPART)  // 320
#define DT_BLKS (MROWS * NHEADS / 4 / 256)  // 128
__global__ __launch_bounds__(256) void convdt2_k(const float* __restrict__ zx,
                                                 const float* __restrict__ cw,
                                                 const float* __restrict__ cb,
                                                 const float* __restrict__ dt_bias,
                                                 const float* __restrict__ A_log,
                                                 float* __restrict__ xin,
                                                 float* __restrict__ bcf,
                                                 float* __restrict__ dtf,
                                                 float* __restrict__ dtAf) {
    int blk = blockIdx.x;
    if (blk < CONV_BLKS) {
        int part = blk % CPART;
        int seg  = (blk / CPART) % SEGS;
        int b    = blk / (CPART * SEGS);
        int cg = part * 256 + threadIdx.x;
        if (cg >= CGRP) return;
        int c = cg * 4;
        float4 k0 = {cw[(c + 0) * 4 + 0], cw[(c + 1) * 4 + 0], cw[(c + 2) * 4 + 0], cw[(c + 3) * 4 + 0]};
        float4 k1 = {cw[(c + 0) * 4 + 1], cw[(c + 1) * 4 + 1], cw[(c + 2) * 4 + 1], cw[(c + 3) * 4 + 1]};
        float4 k2 = {cw[(c + 0) * 4 + 2], cw[(c + 1) * 4 + 2], cw[(c + 2) * 4 + 2], cw[(c + 3) * 4 + 2]};
        float4 k3 = {cw[(c + 0) * 4 + 3], cw[(c + 1) * 4 + 3], cw[(c + 2) * 4 + 3], cw[(c + 3) * 4 + 3]};
        float4 bias = *(const float4*)(cb + c);
        const int t0 = seg * TSEG;
        const float* bp = zx + (size_t)(b * Tdim) * NPAD + DINNER + c;  // +t*NPAD
        float4 w0 = {0.f, 0.f, 0.f, 0.f}, w1 = w0, w2 = w0;
        if (t0 - 3 >= 0) w0 = *(const float4*)(bp + (size_t)(t0 - 3) * NPAD);
        if (t0 - 2 >= 0) w1 = *(const float4*)(bp + (size_t)(t0 - 2) * NPAD);
        if (t0 - 1 >= 0) w2 = *(const float4*)(bp + (size_t)(t0 - 1) * NPAD);
#pragma unroll 4
        for (int t = t0; t < t0 + TSEG; ++t) {
            float4 w3 = *(const float4*)(bp + (size_t)t * NPAD);
            float4 a;
            a.x = bias.x + w0.x * k0.x + w1.x * k1.x + w2.x * k2.x + w3.x * k3.x;
            a.y = bias.y + w0.y * k0.y + w1.y * k1.y + w2.y * k2.y + w3.y * k3.y;
            a.z = bias.z + w0.z * k0.z + w1.z * k1.z + w2.z * k2.z + w3.z * k3.z;
            a.w = bias.w + w0.w * k0.w + w1.w * k1.w + w2.w * k2.w + w3.w * k3.w;
            float4 s = {siluf(a.x), siluf(a.y), siluf(a.z), siluf(a.w)};
            int bt = b * Tdim + t;
            if (c < DINNER) *(float4*)(xin + (size_t)bt * DINNER + c) = s;
            else            *(float4*)(bcf + (size_t)bt * 128 + (c - DINNER)) = s;
            w0 = w1; w1 = w2; w2 = w3;
        }
    } else {
        int idx = (blk - CONV_BLKS) * 256 + threadIdx.x;
        int d4 = idx * 4;
        int bt = d4 >> 6;
        int h = d4 & 63;
        float4 raw = *(const float4*)(zx + (size_t)bt * NPAD + (DINNER + CONVDIM) + h);
        float4 bias = *(const float4*)(dt_bias + h);
        float4 al = *(const float4*)(A_log + h);
        float r[4] = {raw.x + bias.x, raw.y + bias.y, raw.z + bias.z, raw.w + bias.w};
        float A[4] = {-expf(al.x), -expf(al.y), -expf(al.z), -expf(al.w)};
        float4 dtv, dta;
        float* dtp = (float*)&dtv; float* dap = (float*)&dta;
#pragma unroll
        for (int j = 0; j < 4; ++j) {
            float dv = (r[j] > 20.f) ? r[j] : log1pf(expf(r[j]));
            dtp[j] = dv;
            dap[j] = dv * A[j];
        }
        *(float4*)(dtf + bt * 64 + h) = dtv;
        *(float4*)(dtAf + bt * 64 + h) = dta;
    }
}

// ============ chunked SSM scan (SSD decomposition), Q=64 =====================
__global__ __launch_bounds__(256) void chunk_state_k(const float* __restrict__ xin,
                                                     const float* __restrict__ bcf,
                                                     const float* __restrict__ dtf,
                                                     const float* __restrict__ dtAf,
                                                     float* __restrict__ Sst,
                                                     float* __restrict__ laq) {
    const int blk = blockIdx.x;
    const int c = blk & 15, h = (blk >> 4) & 63, b = blk >> 10;
    const int bt0 = b * Tdim + c * QC;
    const int tid = threadIdx.x;

    __shared__ float Bs[QC][68];
    __shared__ float Dx[QC][68];
    __shared__ float wsh[QC];

    if (tid < QC) {
        float v = dtAf[(bt0 + tid) * NHEADS + h];
#pragma unroll
        for (int d = 1; d < 64; d <<= 1) {
            float o = __shfl_up(v, d, 64);
            v += (tid >= d) ? o : 0.f;
        }
        float la63 = __shfl(v, 63, 64);
        wsh[tid] = expf(la63 - v);
        if (tid == 63) laq[blk] = la63;
    }
    __syncthreads();

    const int row = tid >> 2, q = tid & 3;
    {
        float m = wsh[row] * dtf[(bt0 + row) * NHEADS + h];
        const float* xr = xin + (size_t)(bt0 + row) * DINNER + h * 64 + q * 16;
        const float* br = bcf + (size_t)(bt0 + row) * 128 + q * 16;
#pragma unroll
        for (int j = 0; j < 4; ++j) {
            float4 xv = *(const float4*)(xr + j * 4);
            float4 bv = *(const float4*)(br + j * 4);
            *(float4*)&Dx[row][q * 16 + j * 4] = (float4){m * xv.x, m * xv.y, m * xv.z, m * xv.w};
            *(float4*)&Bs[row][q * 16 + j * 4] = bv;
        }
    }
    __syncthreads();

    const int p0 = (tid >> 4) * 4, n0 = (tid & 15) * 4;
    float acc[4][4] = {};
    for (int i = 0; i < QC; ++i) {
        float4 dv = *(const float4*)&Dx[i][p0];
        float4 bv = *(const float4*)&Bs[i][n0];
        float dva[4] = {dv.x, dv.y, dv.z, dv.w};
        float bva[4] = {bv.x, bv.y, bv.z, bv.w};
#pragma unroll
        for (int a = 0; a < 4; ++a)
#pragma unroll
            for (int e = 0; e < 4; ++e) acc[a][e] += dva[a] * bva[e];
    }
    float* Sp = Sst + (size_t)blk * NPAD;
#pragma unroll
    for (int a = 0; a < 4; ++a)
        *(float4*)&Sp[(p0 + a) * 64 + n0] = (float4){acc[a][0], acc[a][1], acc[a][2], acc[a][3]};
}

// Phase B: 256 blocks, each handles half (32 rows) of one (b,h) state prefix
__global__ __launch_bounds__(256) void combine_k(float* __restrict__ Sst,
                                                 const float* __restrict__ laq) {
    const int bh = blockIdx.x >> 1;
    const int half = blockIdx.x & 1;
    const int tid = threadIdx.x;
    float4 r0 = {}, r1 = {};
    for (int c = 0; c < NCHUNK - 1; ++c) {
        float* p = Sst + (size_t)(bh * 16 + c) * NPAD + half * 2048 + tid * 8;
        float P = expf(laq[bh * 16 + c]);
        float4 s0 = ((const float4*)p)[0], s1 = ((const float4*)p)[1];
        r0 = (float4){P * r0.x + s0.x, P * r0.y + s0.y, P * r0.z + s0.z, P * r0.w + s0.w};
        r1 = (float4){P * r1.x + s1.x, P * r1.y + s1.y, P * r1.z + s1.z, P * r1.w + s1.w};
        ((float4*)p)[0] = r0; ((float4*)p)[1] = r1;
    }
}

// ======= chunk_out via MFMA: three 64x64x64 matmuls on the matrix pipe =======
__global__ __launch_bounds__(256) void chunk_out_k2(float* __restrict__ xin,
                                                    const float* __restrict__ bcf,
                                                    const float* __restrict__ dtf,
                                                    const float* __restrict__ dtAf,
                                                    const float* __restrict__ Sst,
                                                    const float* __restrict__ Dp) {
    const int blk = blockIdx.x;
    const int c = blk & 15, h = (blk >> 4) & 63, b = blk >> 10;
    const int bt0 = b * Tdim + c * QC;
    const int tid = threadIdx.x;

    __shared__ unsigned short Csh[64 * 64];   // [t][n]
    __shared__ unsigned short Bsh[64 * 64];   // [s][n]
    __shared__ unsigned short DxT[64 * 64];   // [p][s]
    __shared__ unsigned short Gh [64 * 64];   // [t][s]
    __shared__ unsigned short Hh [64 * 64];   // [p][n]
    __shared__ float lash[QC];

    if (tid < QC) {
        float v = dtAf[(bt0 + tid) * NHEADS + h];
#pragma unroll
        for (int d = 1; d < 64; d <<= 1) {
            float o = __shfl_up(v, d, 64);
            v += (tid >= d) ? o : 0.f;
        }
        lash[tid] = v;
    }

    const int row = tid >> 2, q = tid & 3;    // row = time (t/s) or p for Hh
    {
        float m = dtf[(bt0 + row) * NHEADS + h];
        const float* xr = xin + (size_t)(bt0 + row) * DINNER + h * 64 + q * 16;
        const float* br = bcf + (size_t)(bt0 + row) * 128 + q * 16;
        const float* cr = bcf + (size_t)(bt0 + row) * 128 + 64 + q * 16;
        float xb[16];
        u16x8 cc[2], bb[2];
#pragma unroll
        for (int j = 0; j < 4; ++j) {
            float4 xv = *(const float4*)(xr + j * 4);
            float4 bv = *(const float4*)(br + j * 4);
            float4 cv = *(const float4*)(cr + j * 4);
            xb[j * 4 + 0] = m * xv.x; xb[j * 4 + 1] = m * xv.y;
            xb[j * 4 + 2] = m * xv.z; xb[j * 4 + 3] = m * xv.w;
            int hi = j >> 1, lo = (j & 1) * 4;
            cc[hi][lo + 0] = f2bf(cv.x); cc[hi][lo + 1] = f2bf(cv.y);
            cc[hi][lo + 2] = f2bf(cv.z); cc[hi][lo + 3] = f2bf(cv.w);
            bb[hi][lo + 0] = f2bf(bv.x); bb[hi][lo + 1] = f2bf(bv.y);
            bb[hi][lo + 2] = f2bf(bv.z); bb[hi][lo + 3] = f2bf(bv.w);
        }
        const int base = row * 64;
        const int c0 = ((q * 2) ^ (row & 7)) * 8, c1 = ((q * 2 + 1) ^ (row & 7)) * 8;
        *(u16x8*)&Csh[base + c0] = cc[0];  *(u16x8*)&Csh[base + c1] = cc[1];
        *(u16x8*)&Bsh[base + c0] = bb[0];  *(u16x8*)&Bsh[base + c1] = bb[1];
        // DxT[p][s=row]: transpose scalar writes
#pragma unroll
        for (int k2 = 0; k2 < 16; ++k2) {
            int p = q * 16 + k2;
            DxT[p * 64 + (((row >> 3) ^ (p & 7)) * 8 + (row & 7))] = f2bf(xb[k2]);
        }
        if (c > 0) {   // Hh[p=row][n]: Sst layout is [p][n] -> row-major writes
            const float* Hp = Sst + (size_t)(blk - 1) * NPAD + row * 64 + q * 16;
            u16x8 hh[2];
#pragma unroll
            for (int j = 0; j < 4; ++j) {
                float4 hv = *(const float4*)(Hp + j * 4);
                int hi = j >> 1, lo = (j & 1) * 4;
                hh[hi][lo + 0] = f2bf(hv.x); hh[hi][lo + 1] = f2bf(hv.y);
                hh[hi][lo + 2] = f2bf(hv.z); hh[hi][lo + 3] = f2bf(hv.w);
            }
            *(u16x8*)&Hh[base + c0] = hh[0];  *(u16x8*)&Hh[base + c1] = hh[1];
        }
    }
    __syncthreads();

    const int lane = tid & 63, w = tid >> 6;
    const int t0 = w * 16;                    // wave's t-strip
    const int row16 = lane & 15, quad = lane >> 4;
    const int swz = row16 & 7;

    // ---- M1: acc1[t][s] ----
    f32x4 a1[4];
#pragma unroll
    for (int st = 0; st < 4; ++st) a1[st] = (f32x4){0.f, 0.f, 0.f, 0.f};
#pragma unroll
    for (int kc = 0; kc < 2; ++kc) {
        int g = ((kc * 4 + quad) ^ swz) * 8;
        bf16x8 ca = *(const bf16x8*)&Csh[(t0 + row16) * 64 + g];
#pragma unroll
        for (int st = 0; st < 4; ++st) {
            bf16x8 bs = *(const bf16x8*)&Bsh[(st * 16 + row16) * 64 + g];
            a1[st] = __builtin_amdgcn_mfma_f32_16x16x32_bf16(ca, bs, a1[st], 0, 0, 0);
        }
    }
    // ---- G[t][s] = mask * acc1 * exp(la_t - la_s), write bf16 to Gh ----
    float latv[4];
#pragma unroll
    for (int r = 0; r < 4; ++r) latv[r] = lash[t0 + quad * 4 + r];
#pragma unroll
    for (int st = 0; st < 4; ++st) {
        int s = st * 16 + row16;
        float las = lash[s];
#pragma unroll
        for (int r = 0; r < 4; ++r) {
            int t = t0 + quad * 4 + r;
            float gv = (s <= t) ? a1[st][r] * expf(latv[r] - las) : 0.f;
            Gh[t * 64 + (((s >> 3) ^ (t & 7)) * 8 + (s & 7))] = f2bf(gv);
        }
    }
    __syncthreads();

    // ---- M2 (+M3 when c>0) ----
    f32x4 aS[4], aH[4];
#pragma unroll
    for (int pt = 0; pt < 4; ++pt) { aS[pt] = (f32x4){0.f,0.f,0.f,0.f}; aH[pt] = (f32x4){0.f,0.f,0.f,0.f}; }
#pragma unroll
    for (int kc = 0; kc < 2; ++kc) {
        int g = ((kc * 4 + quad) ^ swz) * 8;
        bf16x8 ga = *(const bf16x8*)&Gh[(t0 + row16) * 64 + g];
#pragma unroll
        for (int pt = 0; pt < 4; ++pt) {
            bf16x8 db = *(const bf16x8*)&DxT[(pt * 16 + row16) * 64 + g];
            aS[pt] = __builtin_amdgcn_mfma_f32_16x16x32_bf16(ga, db, aS[pt], 0, 0, 0);
        }
        if (c > 0) {
            bf16x8 ca = *(const bf16x8*)&Csh[(t0 + row16) * 64 + g];
#pragma unroll
            for (int pt = 0; pt < 4; ++pt) {
                bf16x8 hb = *(const bf16x8*)&Hh[(pt * 16 + row16) * 64 + g];
                aH[pt] = __builtin_amdgcn_mfma_f32_16x16x32_bf16(ca, hb, aH[pt], 0, 0, 0);
            }
        }
    }

    // ---- epilogue: y = accS + e^{la_t} * accH + D*x ----
    float Dh = Dp[h];
    float eA[4];
#pragma unroll
    for (int r = 0; r < 4; ++r) eA[r] = expf(latv[r]);
#pragma unroll
    for (int pt = 0; pt < 4; ++pt)
#pragma unroll
        for (int r = 0; r < 4; ++r) {
            int t = t0 + quad * 4 + r, p = pt * 16 + row16;
            float* xr2 = xin + (size_t)(bt0 + t) * DINNER + h * 64 + p;
            float xv = *xr2;
            float y = aS[pt][r] + Dh * xv;
            if (c > 0) y += eA[r] * aH[pt][r];
            *xr2 = y;
        }
}

// ---------------- y * silu(z), RMSNorm, -> bf16 (strided dest, vec4) ---------
__global__ __launch_bounds__(256) void gate_k(const float* __restrict__ ybf,
                                              const float* __restrict__ zx,
                                              const float* __restrict__ nw,
                                              unsigned short* __restrict__ yg,
                                              int ldyg) {
    int row = blockIdx.x;
    float4 tv[4];
    float s2 = 0.f;
#pragma unroll
    for (int i = 0; i < 4; ++i) {
        int c = (threadIdx.x + 256 * i) * 4;
        float4 y = *(const float4*)(ybf + (size_t)row * DINNER + c);
        float4 z = *(const float4*)(zx + (size_t)row * NPAD + c);
        float4 t = {y.x * siluf(z.x), y.y * siluf(z.y), y.z * siluf(z.z), y.w * siluf(z.w)};
        tv[i] = t;
        s2 += t.x * t.x + t.y * t.y + t.z * t.z + t.w * t.w;
    }
#pragma unroll
    for (int off = 32; off; off >>= 1) s2 += __shfl_down(s2, off);
    __shared__ float rs[4];
    if ((threadIdx.x & 63) == 0) rs[threadIdx.x >> 6] = s2;
    __syncthreads();
    s2 = rs[0] + rs[1] + rs[2] + rs[3];
    float scale = rsqrtf(s2 * (1.f / DINNER) + 1e-5f);
#pragma unroll
    for (int i = 0; i < 4; ++i) {
        int c = (threadIdx.x + 256 * i) * 4;
        float4 w = *(const float4*)(nw + c);
        u16x4 o = {f2bf(tv[i].x * scale * w.x), f2bf(tv[i].y * scale * w.y),
                   f2bf(tv[i].z * scale * w.z), f2bf(tv[i].w * scale * w.w)};
        *(u16x4*)(yg + (size_t)row * ldyg + c) = o;
    }
}

// ---------------- launch ----------------
extern "C" void kernel_launch(void* const* d_in, const int* in_sizes, int n_in,
                              void* d_out, int out_size, void* d_ws, size_t ws_size,
                              hipStream_t stream) {
    const float* x        = (const float*)d_in[0];
    const float* ln_w     = (const float*)d_in[1];
    const float* ln_b     = (const float*)d_in[2];
    const float* in_proj  = (const float*)d_in[3];
    const float* conv_w   = (const float*)d_in[4];
    const float* conv_b   = (const float*)d_in[5];
    const float* dt_bias  = (const float*)d_in[6];
    const float* A_log    = (const float*)d_in[7];
    const float* Dp       = (const float*)d_in[8];
    const float* norm_w   = (const float*)d_in[9];
    const float* out_proj = (const float*)d_in[10];
    float* out = (float*)d_out;
    char* ws = (char*)d_ws;

    // ---- workspace layout ----
    float*          zx   = (float*)(ws + 0);                   // 2048 x 8448 fp32
    unsigned short* wout = (unsigned short*)(ws + 69206016);
    unsigned short* win  = (unsigned short*)(ws + 85983232);
    unsigned short* ubf  = (unsigned short*)(ws + 120586240);
    float*          xin  = (float*)(ws + 85983232);            // reuses win after GEMM1
    float*          bcf  = (float*)(ws + 120586240);           // reuses ubf
    float*          dtf  = (float*)(ws + 121634816);
    float*          dtAf = (float*)(ws + 122159104);
    float*          laq  = (float*)(ws + 122683392);           // 2048 floats
    float*          Sst  = zx + 4096;                          // dead xBC cols of zx
    unsigned short* yg   = (unsigned short*)zx + 8192;         // dead cols (bf16)
    const int       ldyg = 16896;

    prep_k<<<CVT_BLKS + MROWS, 256, 0, stream>>>(in_proj, out_proj, win, wout,
                                                 x, ln_w, ln_b, ubf);
    // GEMM1 (R8-measured 93.5 us): BM=128 -> mb=16, BN=128 -> nb=66, 32 K-tiles
    //        64 KiB LDS -> 2 blocks/CU; grid 1056
    gemm_cr<0, 128, 128, 32><<<66 * 16, 512, 0, stream>>>(ubf, win, zx, nullptr,
                                                          NPAD, DMODEL, DMODEL, 66, 16);
    convdt2_k<<<CONV_BLKS + DT_BLKS, 256, 0, stream>>>(zx, conv_w, conv_b,
                                                       dt_bias, A_log,
                                                       xin, bcf, dtf, dtAf);
    chunk_state_k<<<Bdim * NHEADS * NCHUNK, 256, 0, stream>>>(xin, bcf, dtf, dtAf, Sst, laq);
    combine_k<<<2 * Bdim * NHEADS, 256, 0, stream>>>(Sst, laq);
    chunk_out_k2<<<Bdim * NHEADS * NCHUNK, 256, 0, stream>>>(xin, bcf, dtf, dtAf, Sst, Dp);
    gate_k<<<MROWS, 256, 0, stream>>>(xin, zx, norm_w, yg, ldyg);
    // GEMM2 (R8 config): BM=128 -> mb=16, BN=64 -> nb=32, 64 K-tiles
    //        48 KiB LDS; grid 512 -> 2 blocks/CU
    gemm_cr<1, 128, 64, 64><<<32 * 16, 512, 0, stream>>>(yg, wout, out, x,
                                                         DMODEL, ldyg, DINNER, 32, 16);
}